// Round 2
// baseline (823.142 us; speedup 1.0000x reference)
//
#include <hip/hip_runtime.h>
#include <hip/hip_bf16.h>

// EGCL (EGNN layer): N=384 nodes, V=32 vectors, H=128 feats, U=256 width.
// E = N*(N-1) = 147072 fully-connected edges. Inputs/outputs are FLOAT32
// (reference dtype); compute in bf16 MFMA (harness uses bf16-mode loose
// thresholds). Edges grouped by RECEIVER r (s=(r+1+j')%N) so both segment
// sums are in-workgroup register reductions; [E,256] intermediates never
// touch HBM.

#define NN 384
#define VV 32
#define HH 128
#define UU 256
#define DE 288           // V + 2H
#define EF_S 296         // LDS row stride for 288-wide buf (+8 pad)
#define U_S 264          // LDS row stride for 256-wide bufs (+8 pad)

typedef __bf16 bf16v8 __attribute__((ext_vector_type(8)));
typedef __bf16 bf16v4 __attribute__((ext_vector_type(4)));
typedef float  f32x4  __attribute__((ext_vector_type(4)));

// ---------------- weight repack: P[kt][n][kk] = (bf16)W[kt*32+kk][n] -------
__global__ void repack_kernel(const float* __restrict__ src,
                              __bf16* __restrict__ dst, int Nout, int total) {
    int t = blockIdx.x * 256 + threadIdx.x;
    if (t >= total) return;
    int kt  = t / (Nout * 32);
    int rem = t - kt * Nout * 32;
    int n   = rem >> 5;
    int kk  = rem & 31;
    dst[t] = (__bf16)src[(kt * 32 + kk) * Nout + n];
}

// ---- one 32x256 GEMM layer: Y = silu(scale * X @ W), all waves cooperate ---
__device__ __forceinline__ void gemm256(const __bf16* X, int xs,
                                        const __bf16* __restrict__ P, int KT,
                                        __bf16* Y, int ys, float scale,
                                        int wave, int col, int q) {
    f32x4 acc[2][4] = {};
    const __bf16* xr0 = X + col * xs + q * 8;
    const __bf16* xr1 = X + (16 + col) * xs + q * 8;
    const __bf16* pb  = P + (wave * 64 + col) * 32 + q * 8;
    for (int kt = 0; kt < KT; ++kt) {
        bf16v8 a0 = *(const bf16v8*)(xr0 + kt * 32);
        bf16v8 a1 = *(const bf16v8*)(xr1 + kt * 32);
#pragma unroll
        for (int nt = 0; nt < 4; ++nt) {
            bf16v8 b = *(const bf16v8*)(pb + kt * (UU * 32) + nt * (16 * 32));
            acc[0][nt] = __builtin_amdgcn_mfma_f32_16x16x32_bf16(a0, b, acc[0][nt], 0, 0, 0);
            acc[1][nt] = __builtin_amdgcn_mfma_f32_16x16x32_bf16(a1, b, acc[1][nt], 0, 0, 0);
        }
    }
#pragma unroll
    for (int mt = 0; mt < 2; ++mt)
#pragma unroll
        for (int nt = 0; nt < 4; ++nt)
#pragma unroll
            for (int i = 0; i < 4; ++i) {
                float v = acc[mt][nt][i] * scale;
                v = v / (1.f + __expf(-v));            // silu
                Y[(mt * 16 + q * 4 + i) * ys + wave * 64 + nt * 16 + col] = (__bf16)v;
            }
}

// --------------------------- fused edge kernel -----------------------------
__global__ __launch_bounds__(256, 2)
void edge_kernel(const float* __restrict__ nv, const float* __restrict__ nf,
                 const __bf16* __restrict__ we1p, const __bf16* __restrict__ we2p,
                 const __bf16* __restrict__ wx1p, const __bf16* __restrict__ wx2p,
                 const __bf16* __restrict__ wxlp, const float* __restrict__ bxl,
                 const float* __restrict__ winf,
                 float* __restrict__ shiftws, float* __restrict__ miws) {
    __shared__ __align__(16) __bf16 efb[32 * EF_S];   // edge_feat, later t1
    __shared__ __align__(16) __bf16 h1b[32 * U_S];    // h1, later t2
    __shared__ __align__(16) __bf16 mb [32 * U_S];    // m_ij (kept to tile end)
    __shared__ float  vecb[32 * 32 * 3];
    __shared__ float  lenb[32 * 32];
    __shared__ float  phixb[32 * 32];   // phi_x; also gate-partial scratch
    __shared__ float  gateb[32];

    const int tid  = threadIdx.x;
    const int wave = tid >> 6;
    const int lane = tid & 63;
    const int col  = lane & 15;
    const int q    = lane >> 4;
    const int r     = blockIdx.y;
    const int chunk = blockIdx.x;

    float macc = 0.f;                   // per-thread m_i[r][tid] accumulator
    float sreg = 0.f;                   // per-thread shifts[r][v][c] (tid<96)
    const int sv = tid / 3, sc = tid - sv * 3;

    for (int t = 0; t < 4; ++t) {
        const int jbase = chunk * 128 + t * 32;
        __syncthreads();  // previous tile's reductions done before overwrite

        // ---- stage edge features: [len2 | nf[s] | nf[r]] + vec/len ----
        for (int p = tid; p < 1024; p += 256) {
            int i = p >> 5, v = p & 31;
            int s = r + 1 + jbase + i; if (s >= NN) s -= NN;
            const float* pr = nv + (r * 32 + v) * 3;
            const float* ps = nv + (s * 32 + v) * 3;
            float d0 = pr[0] - ps[0];
            float d1 = pr[1] - ps[1];
            float d2 = pr[2] - ps[2];
            float l2 = d0 * d0 + d1 * d1 + d2 * d2;
            vecb[p * 3 + 0] = d0; vecb[p * 3 + 1] = d1; vecb[p * 3 + 2] = d2;
            lenb[p] = sqrtf(fmaxf(l2, 1e-20f));
            efb[i * EF_S + v] = (__bf16)l2;
        }
        for (int p = tid; p < 1024; p += 256) {
            int i = p >> 5, hc = (p & 31) << 2;
            int s = r + 1 + jbase + i; if (s >= NN) s -= NN;
            float4 fs = *(const float4*)(nf + s * HH + hc);
            float4 fr = *(const float4*)(nf + r * HH + hc);
            bf16v4 bs = { (__bf16)fs.x, (__bf16)fs.y, (__bf16)fs.z, (__bf16)fs.w };
            bf16v4 br = { (__bf16)fr.x, (__bf16)fr.y, (__bf16)fr.z, (__bf16)fr.w };
            *(bf16v4*)&efb[i * EF_S + 32 + hc]  = bs;
            *(bf16v4*)&efb[i * EF_S + 160 + hc] = br;
        }
        __syncthreads();

        // ---- h1 = silu(ef @ We1 / sqrt(288)) ----
        gemm256(efb, EF_S, we1p, 9, h1b, U_S, 0.05892556509887896f, wave, col, q);
        __syncthreads();
        // ---- m = silu(h1 @ We2 / 16) ----
        gemm256(h1b, U_S, we2p, 8, mb, U_S, 0.0625f, wave, col, q);
        __syncthreads();

        // ---- gate e = sigmoid(m @ Winf / 16); partials in phixb scratch ----
        {
            int i = tid >> 3, kp = (tid & 7) * 32;
            float a = 0.f;
            for (int k = 0; k < 32; ++k)
                a += (float)mb[i * U_S + kp + k] * winf[kp + k];
            phixb[tid] = a;
        }
        __syncthreads();
        if (tid < 32) {
            float a = 0.f;
            for (int p8 = 0; p8 < 8; ++p8) a += phixb[tid * 8 + p8];
            gateb[tid] = (jbase + tid == NN - 1) ? 0.f      // self-edge pad
                                                 : 1.f / (1.f + __expf(-a * 0.0625f));
        }

        // ---- t1 = silu(m @ Wx1 / 16) into efb; t2 = silu(t1 @ Wx2 / 16) ----
        gemm256(mb, U_S, wx1p, 8, efb, EF_S, 0.0625f, wave, col, q);
        __syncthreads();
        gemm256(efb, EF_S, wx2p, 8, h1b, U_S, 0.0625f, wave, col, q);
        __syncthreads();

        // ---- phi_x = t2 @ Wxl + bxl   (32 outputs; one 16x16 tile/wave) ----
        {
            int mt = wave >> 1, nt = wave & 1;
            f32x4 acc = {0.f, 0.f, 0.f, 0.f};
            const __bf16* xr = h1b + (mt * 16 + col) * U_S + q * 8;
#pragma unroll
            for (int kt = 0; kt < 8; ++kt) {
                bf16v8 a = *(const bf16v8*)(xr + kt * 32);
                bf16v8 b = *(const bf16v8*)(wxlp + (kt * 32 + nt * 16 + col) * 32 + q * 8);
                acc = __builtin_amdgcn_mfma_f32_16x16x32_bf16(a, b, acc, 0, 0, 0);
            }
            float bias = bxl[nt * 16 + col];
#pragma unroll
            for (int i = 0; i < 4; ++i)
                phixb[(mt * 16 + q * 4 + i) * 32 + nt * 16 + col] = acc[i] + bias;
        }
        __syncthreads();

        // ---- accumulate shifts (self-edge has vec=0, masks itself) ----
        if (tid < 96) {
            for (int i = 0; i < 32; ++i) {
                float ph = phixb[i * 32 + sv];
                sreg += ph * vecb[(i * 32 + sv) * 3 + sc] / (1.f + lenb[i * 32 + sv]);
            }
        }
        // ---- accumulate m_i (gate already zeroed on self-edge) ----
        for (int i = 0; i < 32; ++i)
            macc += (float)mb[i * U_S + tid] * gateb[i];
    }

    atomicAdd(&miws[r * UU + tid], macc);
    if (tid < 96) atomicAdd(&shiftws[r * 96 + tid], sreg);
}

// --------------------------- node-level epilogue ---------------------------
__global__ __launch_bounds__(256, 2)
void node_kernel(const float* __restrict__ nv, const float* __restrict__ nf,
                 const float* __restrict__ Wh1, const float* __restrict__ Wh2,
                 const float* __restrict__ Whl,
                 const float* __restrict__ shiftws, const float* __restrict__ miws,
                 float* __restrict__ out) {
    __shared__ float xs[384];
    __shared__ float h1[256];
    __shared__ float h2[256];
    const int n = blockIdx.x, tid = threadIdx.x;

    xs[tid] = miws[n * UU + tid];
    if (tid < 128) xs[256 + tid] = nf[n * HH + tid];
    if (tid < 96)  // vectors_out = nv + shifts/(N-1)
        out[n * 96 + tid] = nv[n * 96 + tid] + shiftws[n * 96 + tid] * (1.f / 383.f);
    __syncthreads();

    float a = 0.f;
    for (int k = 0; k < 384; ++k) a += xs[k] * Wh1[k * 256 + tid];
    a *= 0.05103103630798288f;              // 1/sqrt(384)
    h1[tid] = a / (1.f + __expf(-a));
    __syncthreads();

    a = 0.f;
    for (int k = 0; k < 256; ++k) a += h1[k] * Wh2[k * 256 + tid];
    a *= 0.0625f;
    h2[tid] = a / (1.f + __expf(-a));
    __syncthreads();

    if (tid < 128) {
        a = 0.f;
        for (int k = 0; k < 256; ++k) a += h2[k] * Whl[k * 128 + tid];
        out[NN * 96 + n * HH + tid] = a * 0.0625f + nf[n * HH + tid];
    }
}

// ------------------------------- launcher ----------------------------------
extern "C" void kernel_launch(void* const* d_in, const int* in_sizes, int n_in,
                              void* d_out, int out_size, void* d_ws, size_t ws_size,
                              hipStream_t stream) {
    const float* nv   = (const float*)d_in[0];
    const float* nf   = (const float*)d_in[1];
    const float* We1  = (const float*)d_in[2];
    const float* We2  = (const float*)d_in[3];
    const float* Wx1  = (const float*)d_in[4];
    const float* Wx2  = (const float*)d_in[5];
    const float* Wxl  = (const float*)d_in[6];
    const float* bxl  = (const float*)d_in[7];
    const float* Winf = (const float*)d_in[8];
    const float* Wh1  = (const float*)d_in[9];
    const float* Wh2  = (const float*)d_in[10];
    const float* Whl  = (const float*)d_in[11];
    float* out = (float*)d_out;

    char* ws = (char*)d_ws;
    float*  shiftws = (float*)ws;                       // 384*96*4  = 147456 B
    float*  miws    = (float*)(ws + 147456);            // 384*256*4 = 393216 B
    __bf16* we1p    = (__bf16*)(ws + 540672);           // 9*256*32*2 = 147456 B
    __bf16* we2p    = (__bf16*)(ws + 688128);           // 8*256*32*2 = 131072 B
    __bf16* wx1p    = (__bf16*)(ws + 819200);
    __bf16* wx2p    = (__bf16*)(ws + 950272);
    __bf16* wxlp    = (__bf16*)(ws + 1081344);          // 8*32*32*2 = 16384 B

    hipMemsetAsync(d_ws, 0, 540672, stream);            // zero accumulators

    repack_kernel<<<dim3((73728 + 255) / 256), 256, 0, stream>>>(We1, we1p, 256, 73728);
    repack_kernel<<<dim3((65536 + 255) / 256), 256, 0, stream>>>(We2, we2p, 256, 65536);
    repack_kernel<<<dim3((65536 + 255) / 256), 256, 0, stream>>>(Wx1, wx1p, 256, 65536);
    repack_kernel<<<dim3((65536 + 255) / 256), 256, 0, stream>>>(Wx2, wx2p, 256, 65536);
    repack_kernel<<<dim3((8192  + 255) / 256), 256, 0, stream>>>(Wxl, wxlp, 32, 8192);

    edge_kernel<<<dim3(3, NN), 256, 0, stream>>>(nv, nf, we1p, we2p, wx1p, wx2p,
                                                 wxlp, bxl, Winf, shiftws, miws);
    node_kernel<<<dim3(NN), 256, 0, stream>>>(nv, nf, Wh1, Wh2, Whl,
                                              shiftws, miws, out);
}